// Round 3
// baseline (508.537 us; speedup 1.0000x reference)
//
#include <hip/hip_runtime.h>
#include <math.h>

#define NN 102400
#define FD 128
#define KC 16
#define BG 64
#define NPG 1600
#define NE 3276800
#define HB 1024          // hist/scatter blocks
#define EH (NE / HB)     // 3200 edges per hist/scatter block

__device__ __forceinline__ void glob_addf(float* p, float v) {
  unsafeAtomicAdd(p, v);
}
__device__ __forceinline__ unsigned short f2bf(float f) {
  unsigned u = __float_as_uint(f);
  u += 0x7FFFu + ((u >> 16) & 1u);
  return (unsigned short)(u >> 16);
}
__device__ __forceinline__ float bf2f(unsigned short h) {
  return __uint_as_float(((unsigned)h) << 16);
}

// -------------------- s = softmax(softmax(x@W+b)) --------------------
__global__ __launch_bounds__(256) void k_s(const float* __restrict__ x,
    const float* __restrict__ W, const float* __restrict__ bb,
    float* __restrict__ s) {
  const int t = threadIdx.x;
  const int n = blockIdx.x * 256 + t;
  float acc[KC];
#pragma unroll
  for (int k = 0; k < KC; ++k) acc[k] = bb[k];
  const float4* xr = (const float4*)(x + (size_t)n * FD);
#pragma unroll 4
  for (int c = 0; c < FD / 4; ++c) {
    float4 v = xr[c];
    const float* wr = W + c * 4 * KC;
#pragma unroll
    for (int k = 0; k < KC; ++k)
      acc[k] += v.x * wr[k] + v.y * wr[KC + k] + v.z * wr[2 * KC + k] + v.w * wr[3 * KC + k];
  }
#pragma unroll
  for (int r = 0; r < 2; ++r) {
    float m = acc[0];
#pragma unroll
    for (int k = 1; k < KC; ++k) m = fmaxf(m, acc[k]);
    float sum = 0.f;
#pragma unroll
    for (int k = 0; k < KC; ++k) { acc[k] = expf(acc[k] - m); sum += acc[k]; }
    float inv = 1.f / sum;
#pragma unroll
    for (int k = 0; k < KC; ++k) acc[k] *= inv;
  }
  float4* so = (float4*)(s + (size_t)n * KC);
  so[0] = make_float4(acc[0], acc[1], acc[2], acc[3]);
  so[1] = make_float4(acc[4], acc[5], acc[6], acc[7]);
  so[2] = make_float4(acc[8], acc[9], acc[10], acc[11]);
  so[3] = make_float4(acc[12], acc[13], acc[14], acc[15]);
}

// -------------------- counting sort by graph: histogram --------------------
__global__ __launch_bounds__(256) void k_hist(const int* __restrict__ esrc,
    unsigned* __restrict__ blkhist) {
  __shared__ unsigned h[BG];
  const int t = threadIdx.x, b = blockIdx.x;
  if (t < BG) h[t] = 0u;
  __syncthreads();
  const int e0 = b * EH;
  for (int i = t; i < EH; i += 256) {
    unsigned g = (unsigned)esrc[e0 + i] / (unsigned)NPG;
    atomicAdd(&h[g], 1u);
  }
  __syncthreads();
  if (t < BG) blkhist[t * HB + b] = h[t];
}

// -------------------- parallel scan, stage A: per-graph scan over 1024 blocks --------------------
__global__ __launch_bounds__(1024) void k_scan_a(unsigned* __restrict__ blkhist,
    unsigned* __restrict__ gtot) {
  __shared__ unsigned wsum[16];
  const int t = threadIdx.x, g = blockIdx.x;
  const int lane = t & 63;
  unsigned v = blkhist[g * HB + t];
  unsigned inc = v;
#pragma unroll
  for (int o = 1; o < 64; o <<= 1) {
    unsigned n = __shfl_up(inc, o, 64);
    if (lane >= o) inc += n;
  }
  if (lane == 63) wsum[t >> 6] = inc;
  __syncthreads();
  if (t == 0) {
    unsigned run = 0;
#pragma unroll
    for (int i = 0; i < 16; ++i) { unsigned c = wsum[i]; wsum[i] = run; run += c; }
    gtot[g] = run;
  }
  __syncthreads();
  blkhist[g * HB + t] = inc - v + wsum[t >> 6];
}

// -------------------- scan stage B: graph bases --------------------
__global__ void k_scan_b(const unsigned* __restrict__ gtot, unsigned* __restrict__ gbase) {
  if (threadIdx.x == 0) {
    unsigned run = 0;
    for (int g = 0; g < BG; ++g) { gbase[g] = run; run += gtot[g]; }
    gbase[BG] = run;
  }
}

// -------------------- scatter edges into per-graph buckets (w as bf16) --------------------
__global__ __launch_bounds__(256) void k_scatter(const float* __restrict__ ew,
    const int* __restrict__ esrc, const int* __restrict__ edst,
    const unsigned* __restrict__ blkhist, const unsigned* __restrict__ gbase,
    unsigned short* __restrict__ swb, unsigned* __restrict__ spk) {
  __shared__ unsigned h[BG];
  __shared__ unsigned off[BG];
  const int t = threadIdx.x, b = blockIdx.x;
  if (t < BG) { h[t] = 0u; off[t] = gbase[t] + blkhist[t * HB + b]; }
  __syncthreads();
  const int e0 = b * EH;
  for (int i = t; i < EH; i += 256) {
    int e = e0 + i;
    int s0 = esrc[e], d0 = edst[e];
    float w = ew[e];
    unsigned g = (unsigned)s0 / (unsigned)NPG;
    unsigned r = atomicAdd(&h[g], 1u);
    unsigned pos = off[g] + r;
    spk[pos] = (unsigned)(s0 - (int)g * NPG) | ((unsigned)(d0 - (int)g * NPG) << 11);
    swb[pos] = f2bf(w);
  }
}

// -------------------- M[i] = sum_{e:src=i} w*s_dst  (LDS accum, per graph x l-half) --------------------
// also den = sum_e w*||s_dst||^2  folded in
__global__ __launch_bounds__(1024, 8) void k_M(const float* __restrict__ s,
    const unsigned short* __restrict__ swb, const unsigned* __restrict__ spk,
    const unsigned* __restrict__ gbase, float* __restrict__ M, float* __restrict__ den) {
  __shared__ float mlds[NPG * 9];   // 57,600 B, stride-9 pad vs 32 banks
  __shared__ float scr[16];
  const int t = threadIdx.x;
  const int g = blockIdx.x & 63;
  const int r = blockIdx.x >> 6;    // 0..7
  const int sub = r & 3, lh = r >> 2;
  for (int i = t; i < NPG * 9; i += 1024) mlds[i] = 0.f;
  __syncthreads();
  const unsigned beg = gbase[g], end = gbase[g + 1];
  const unsigned nch = (end - beg + 7u) >> 3;   // 8-edge chunks
  const int lane = t & 63, wv = t >> 6;
  const int eg = lane >> 3, l = lane & 7;
  const int wid = sub * 16 + wv;                // 0..63 waves sweep this graph's chunks
  const float* sG = s + (size_t)g * NPG * KC + lh * 8 + l;
  float dacc = 0.f;
#pragma unroll 2
  for (unsigned ch = wid; ch < nch; ch += 64) {
    unsigned e = beg + (ch << 3) + (unsigned)eg;
    bool ok = e < end;
    float w = 0.f;
    unsigned pk = 0u;
    if (ok) { w = bf2f(swb[e]); pk = spk[e]; }
    int src = (int)(pk & 0x7FFu), dst = (int)(pk >> 11);
    float v = sG[(size_t)dst * KC];
    float tw = w * v;
    atomicAdd(&mlds[src * 9 + l], tw);          // ds_add_f32
    dacc = fmaf(tw, v, dacc);
  }
  __syncthreads();
  for (int i = t; i < NPG * 8; i += 1024) {
    int node = i >> 3, c = i & 7;
    glob_addf(M + (size_t)(g * NPG + node) * KC + lh * 8 + c, mlds[node * 9 + c]);
  }
#pragma unroll
  for (int o = 32; o > 0; o >>= 1) dacc += __shfl_down(dacc, o, 64);
  if ((t & 63) == 0) scr[t >> 6] = dacc;
  __syncthreads();
  if (t == 0) {
    float sum = 0.f;
#pragma unroll
    for (int i = 0; i < 16; ++i) sum += scr[i];
    glob_addf(den, sum);
  }
}

// -------------------- node pass: CC = S^T S, out_x = S^T X, adj = S^T M --------------------
__global__ __launch_bounds__(256, 8) void k_mid(const float* __restrict__ s,
    const float* __restrict__ x, const float* __restrict__ M,
    float* __restrict__ cc_raw, float* __restrict__ outx_raw,
    float* __restrict__ adj_raw) {
  __shared__ float st[100 * KC];
  __shared__ float mt[100 * KC];
  const int t = threadIdx.x;
  const int g = blockIdx.x >> 4, sub = blockIdx.x & 15;
  const int n0 = g * NPG + sub * 100;
  const int j = t & 127, h = t >> 7;
  const int kc = t >> 4, lc = t & 15;
  for (int u = t; u < 100 * KC; u += 256) {
    st[u] = s[(size_t)n0 * KC + u];
    mt[u] = M[(size_t)n0 * KC + u];
  }
  __syncthreads();
  float accX[8] = {0.f, 0.f, 0.f, 0.f, 0.f, 0.f, 0.f, 0.f};
  float accC = 0.f, accA = 0.f;
  for (int i = 0; i < 100; ++i) {
    const float xv = x[(size_t)(n0 + i) * FD + j];
    const float* si = st + i * KC;
#pragma unroll
    for (int kk = 0; kk < 8; ++kk) accX[kk] = fmaf(si[h * 8 + kk], xv, accX[kk]);
    const float ck = si[kc];
    accC = fmaf(ck, si[lc], accC);
    accA = fmaf(ck, mt[i * KC + lc], accA);
  }
#pragma unroll
  for (int kk = 0; kk < 8; ++kk)
    glob_addf(outx_raw + g * 2048 + (h * 8 + kk) * 128 + j, accX[kk]);
  glob_addf(cc_raw + g * 256 + t, accC);
  glob_addf(adj_raw + g * 256 + t, accA);
}

// -------------------- finalize: adj normalize, trace, ortho, SELU --------------------
__device__ __forceinline__ float bred(float v, float* scr) {
#pragma unroll
  for (int o = 32; o > 0; o >>= 1) v += __shfl_down(v, o, 64);
  __syncthreads();
  if ((threadIdx.x & 63) == 0) scr[threadIdx.x >> 6] = v;
  __syncthreads();
  return scr[0] + scr[1] + scr[2] + scr[3];
}

__global__ __launch_bounds__(256) void k_post(const float* __restrict__ adj_raw,
    const float* __restrict__ cc_raw, const float* __restrict__ outx_raw,
    float* __restrict__ out, float* __restrict__ ws_num, float* __restrict__ ws_ortho) {
  const int b = blockIdx.x, t = threadIdx.x;
  const int k = t >> 4, l = t & 15;
  __shared__ float m[16 * 17];
  __shared__ float dk[16];
  __shared__ float scr[4];
  const float raw = adj_raw[b * 256 + t];
  const float masked = (k == l) ? 0.f : raw;
  m[k * 17 + l] = masked;
  __syncthreads();
  if (t < 16) {
    float rs = 0.f;
#pragma unroll
    for (int ll = 0; ll < 16; ++ll) rs += m[t * 17 + ll];
    dk[t] = sqrtf(rs) + 1e-12f;
  }
  __syncthreads();
  out[131072 + b * 256 + t] = masked / (dk[k] * dk[l]);
  float tr = bred((k == l) ? raw : 0.f, scr);
  if (t == 0) glob_addf(ws_num, tr);
  const float c = cc_raw[b * 256 + t];
  float n2 = bred(c * c, scr);
  float diff = c / sqrtf(n2) - ((k == l) ? 0.25f : 0.f);
  float d2 = bred(diff * diff, scr);
  if (t == 0) glob_addf(ws_ortho, sqrtf(d2));
  for (int idx = b * 256 + t; idx < 131072; idx += 16384) {
    float xv = outx_raw[idx];
    out[idx] = xv > 0.f ? 1.0507009873554805f * xv
                        : 1.0507009873554805f * 1.6732632423543772f * expm1f(xv);
  }
}

__global__ void k_last(const float* __restrict__ scal, float* __restrict__ out) {
  out[147456] = -scal[1] / scal[0];      // -num/den
  out[147457] = scal[2] * (1.f / 64.f);  // mean ortho
}

// -------------------- launch --------------------
extern "C" void kernel_launch(void* const* d_in, const int* in_sizes, int n_in,
                              void* d_out, int out_size, void* d_ws, size_t ws_size,
                              hipStream_t stream) {
  const float* x  = (const float*)d_in[0];
  const float* W  = (const float*)d_in[1];
  const float* bb = (const float*)d_in[2];
  const float* ew = (const float*)d_in[3];
  const int* esrc = (const int*)d_in[4];
  const int* edst = (const int*)d_in[5];
  float* out = (float*)d_out;
  float* ws = (float*)d_ws;

  float* s_buf   = ws;                                   // 1,638,400 f
  float* M       = s_buf + (size_t)NN * KC;              // 1,638,400 f
  float* adj_raw = M + (size_t)NN * KC;                  // 16,384 f
  float* cc_raw  = adj_raw + 16384;                      // 16,384 f
  float* outx    = cc_raw + 16384;                       // 131,072 f
  float* scal    = outx + 131072;                        // 8 f: [0]=den [1]=num [2]=ortho
  unsigned* blkhist = (unsigned*)(scal + 8);             // 65,536 u
  unsigned* gtot    = blkhist + (size_t)BG * HB;         // 64 u
  unsigned* gbase   = gtot + BG;                         // 68 u (65 used)
  unsigned* spk  = gbase + 68;                           // NE u
  unsigned short* swb = (unsigned short*)(spk + NE);     // NE u16
  // total ~= 33.69 MB (matches the 33.69 MB proven available in R2)

  hipMemsetAsync(M, 0, (size_t)((size_t)NN * KC + 16384 + 16384 + 131072 + 8) * sizeof(float), stream);
  k_s<<<NN / 256, 256, 0, stream>>>(x, W, bb, s_buf);
  k_hist<<<HB, 256, 0, stream>>>(esrc, blkhist);
  k_scan_a<<<BG, 1024, 0, stream>>>(blkhist, gtot);
  k_scan_b<<<1, 64, 0, stream>>>(gtot, gbase);
  k_scatter<<<HB, 256, 0, stream>>>(ew, esrc, edst, blkhist, gbase, swb, spk);
  k_M<<<BG * 8, 1024, 0, stream>>>(s_buf, swb, spk, gbase, M, scal);
  k_mid<<<BG * 16, 256, 0, stream>>>(s_buf, x, M, cc_raw, outx, adj_raw);
  k_post<<<64, 256, 0, stream>>>(adj_raw, cc_raw, outx, out, scal + 1, scal + 2);
  k_last<<<1, 1, 0, stream>>>(scal, out);
}